// Round 10
// baseline (182.550 us; speedup 1.0000x reference)
//
#include <hip/hip_runtime.h>

// SmoothL1 (beta=0.5) masked sum reduction, N = 16M fixed.
// sl1 = ad < 0.5 ? d*d : ad - 0.25  (0.5*d*d/0.5 == d*d exactly: pow-2)
// mask: ad >= 1.0f/len; out[0] = sum(mask ? sl1 : 0)
//
// Ladder (warm kernel us): plain=73 | sc1=74-75 | nt d1=51 | nt d2=45.6 |
// nt d3=44.6 (6144 cur x 32KB) | R13 3072x64KB d6 ~40 | R14 1536x128KB d6
// ~37.9 (5.3 TB/s; bench 178.6->176.0). Harness fill kernel = 6.6 TB/s
// pure-write reference -> still ~20% headroom. Cursor-count x run-length
// axis is the live lever (DRAM page/activate locality).
//
// R15: continue the axis single-variable: GRID 512->256 (1 block/CU, 768
// cursors x 256KB sequential runs), ITERS=64, depth stays 6.
// Checks: 18.9MB in flight >> Little's-law need; VALU (~160cy/wave/iter incl
// IEEE divide) < memory service (~287cy/wave/iter) even at 1 wave/SIMD.
// Predict: continues -> ~35-36us (bench ~173-174); neutral -> axis saturated,
// settle at R14; regress -> channel under-coverage, revert.

#define N_TOTAL 16777216
#define NVEC    (N_TOTAL / 4)       // 4194304 vec4 groups
#define BLOCK   256
#define GRID    256                 // 1 block/CU, 4 waves/CU
#define ITERS   (NVEC / (BLOCK * GRID))   // 64 iterations/thread, exact cover

typedef float f32x4 __attribute__((ext_vector_type(4)));
typedef int   i32x4 __attribute__((ext_vector_type(4)));

__device__ __forceinline__ float sl1_term(float o, float l, int len) {
    float d  = o - l;
    float ad = fabsf(d);
    float v  = (ad < 0.5f) ? (d * d) : (ad - 0.25f);
    float boundary = 1.0f / (float)len;   // IEEE divide; matches jnp 1/len
    return (ad >= boundary) ? v : 0.0f;
}

__device__ __forceinline__ float consume4(f32x4 o, f32x4 l, i32x4 n) {
    float s = 0.0f;
    s += sl1_term(o.x, l.x, n.x);
    s += sl1_term(o.y, l.y, n.y);
    s += sl1_term(o.z, l.z, n.z);
    s += sl1_term(o.w, l.w, n.w);
    return s;
}

__global__ __launch_bounds__(BLOCK, 1) void RegressionLoss_45440753992375_kernel(
        const float* __restrict__ outs,
        const float* __restrict__ labels,
        const int*   __restrict__ lens,
        float* __restrict__ out) {
    const f32x4* o4 = (const f32x4*)outs;
    const f32x4* l4 = (const f32x4*)labels;
    const i32x4* n4 = (const i32x4*)lens;

    // Block-contiguous 256KB span per array; thread strides BLOCK (4KB steps).
    const int base = blockIdx.x * (BLOCK * ITERS) + threadIdx.x;

    // Pipeline prologue: iterations 0..5 in flight (18 loads, 288B/thread).
    f32x4 oA = __builtin_nontemporal_load(o4 + base);
    f32x4 lA = __builtin_nontemporal_load(l4 + base);
    i32x4 nA = __builtin_nontemporal_load(n4 + base);

    f32x4 oB = __builtin_nontemporal_load(o4 + base + 1 * BLOCK);
    f32x4 lB = __builtin_nontemporal_load(l4 + base + 1 * BLOCK);
    i32x4 nB = __builtin_nontemporal_load(n4 + base + 1 * BLOCK);

    f32x4 oC = __builtin_nontemporal_load(o4 + base + 2 * BLOCK);
    f32x4 lC = __builtin_nontemporal_load(l4 + base + 2 * BLOCK);
    i32x4 nC = __builtin_nontemporal_load(n4 + base + 2 * BLOCK);

    f32x4 oD = __builtin_nontemporal_load(o4 + base + 3 * BLOCK);
    f32x4 lD = __builtin_nontemporal_load(l4 + base + 3 * BLOCK);
    i32x4 nD = __builtin_nontemporal_load(n4 + base + 3 * BLOCK);

    f32x4 oE = __builtin_nontemporal_load(o4 + base + 4 * BLOCK);
    f32x4 lE = __builtin_nontemporal_load(l4 + base + 4 * BLOCK);
    i32x4 nE = __builtin_nontemporal_load(n4 + base + 4 * BLOCK);

    f32x4 oF = __builtin_nontemporal_load(o4 + base + 5 * BLOCK);
    f32x4 lF = __builtin_nontemporal_load(l4 + base + 5 * BLOCK);
    i32x4 nF = __builtin_nontemporal_load(n4 + base + 5 * BLOCK);

    float acc = 0.0f;
    #pragma unroll
    for (int it = 0; it < ITERS - 6; ++it) {
        // Issue iteration it+6 (21 outstanding peak) before consuming it.
        const int idx = base + (it + 6) * BLOCK;
        f32x4 oG = __builtin_nontemporal_load(o4 + idx);
        f32x4 lG = __builtin_nontemporal_load(l4 + idx);
        i32x4 nG = __builtin_nontemporal_load(n4 + idx);

        acc += consume4(oA, lA, nA);

        // Rotate stages (register renaming; loop fully unrolled).
        oA = oB; lA = lB; nA = nB;
        oB = oC; lB = lC; nB = nC;
        oC = oD; lC = lD; nC = nD;
        oD = oE; lD = lE; nD = nE;
        oE = oF; lE = lF; nE = nF;
        oF = oG; lF = lG; nF = nG;
    }
    acc += consume4(oA, lA, nA);   // iteration ITERS-6
    acc += consume4(oB, lB, nB);   // iteration ITERS-5
    acc += consume4(oC, lC, nC);   // iteration ITERS-4
    acc += consume4(oD, lD, nD);   // iteration ITERS-3
    acc += consume4(oE, lE, nE);   // iteration ITERS-2
    acc += consume4(oF, lF, nF);   // iteration ITERS-1

    // wave-64 shuffle reduction
    #pragma unroll
    for (int off = 32; off > 0; off >>= 1)
        acc += __shfl_down(acc, off, 64);

    __shared__ float smem[BLOCK / 64];
    const int lane = threadIdx.x & 63;
    const int wid  = threadIdx.x >> 6;
    if (lane == 0) smem[wid] = acc;
    __syncthreads();
    if (threadIdx.x == 0) {
        float bsum = smem[0] + smem[1] + smem[2] + smem[3];
        atomicAdd(out, bsum);   // device-scope by default on CDNA
    }
}

extern "C" void kernel_launch(void* const* d_in, const int* in_sizes, int n_in,
                              void* d_out, int out_size, void* d_ws, size_t ws_size,
                              hipStream_t stream) {
    const float* outs   = (const float*)d_in[0];
    const float* labels = (const float*)d_in[1];
    const int*   lens   = (const int*)d_in[2];
    float* out = (float*)d_out;

    // d_out is poisoned 0xAA before every timed launch — zero it on-stream.
    hipMemsetAsync(out, 0, sizeof(float), stream);

    RegressionLoss_45440753992375_kernel<<<GRID, BLOCK, 0, stream>>>(outs, labels, lens, out);
}

// Round 11
// 177.367 us; speedup vs baseline: 1.0292x; 1.0292x over previous
//
#include <hip/hip_runtime.h>

// SmoothL1 (beta=0.5) masked sum reduction, N = 16M fixed.
// sl1 = ad < 0.5 ? d*d : ad - 0.25  (0.5*d*d/0.5 == d*d exactly: pow-2)
// mask: ad >= 1.0f/len; out[0] = sum(mask ? sl1 : 0)
//
// Ladder (warm kernel us): plain=73 | sc1=74-75 | nt d1=51 | nt d2=45.6 |
// nt d3=44.6 (6144cur) | R13 3072x64KB d6 ~40 | R14 1536x128KB d6 ~37.9
// (5.3 TB/s) | R15 768x256KB d6 = 41.7 REGRESS (under-coverage; occupancy
// 9%). Cursor axis optimum = R14. Effective-BW vs cursors: 4.5/5.0/5.3/4.8.
//
// R16: depth probe at the R14 optimum, single-variable: depth 6->8
// (24 loads, 384B/thread in flight, ~25MB device-wide). GRID=512, ITERS=32
// unchanged. launch_bounds(256,2): VGPR est ~115 < 128 keeps 2 blocks/CU.
// Predict: concurrency-trim -> 36-37us; neutral -> all axes saturated,
// declare read roofline next round; regress -> VGPR>128 occupancy halved,
// revert to depth 6.

#define N_TOTAL 16777216
#define NVEC    (N_TOTAL / 4)       // 4194304 vec4 groups
#define BLOCK   256
#define GRID    512                 // 2 blocks/CU, 8 waves/CU
#define ITERS   (NVEC / (BLOCK * GRID))   // 32 iterations/thread, exact cover
#define DEPTH   8

typedef float f32x4 __attribute__((ext_vector_type(4)));
typedef int   i32x4 __attribute__((ext_vector_type(4)));

__device__ __forceinline__ float sl1_term(float o, float l, int len) {
    float d  = o - l;
    float ad = fabsf(d);
    float v  = (ad < 0.5f) ? (d * d) : (ad - 0.25f);
    float boundary = 1.0f / (float)len;   // IEEE divide; matches jnp 1/len
    return (ad >= boundary) ? v : 0.0f;
}

__device__ __forceinline__ float consume4(f32x4 o, f32x4 l, i32x4 n) {
    float s = 0.0f;
    s += sl1_term(o.x, l.x, n.x);
    s += sl1_term(o.y, l.y, n.y);
    s += sl1_term(o.z, l.z, n.z);
    s += sl1_term(o.w, l.w, n.w);
    return s;
}

__global__ __launch_bounds__(BLOCK, 2) void RegressionLoss_45440753992375_kernel(
        const float* __restrict__ outs,
        const float* __restrict__ labels,
        const int*   __restrict__ lens,
        float* __restrict__ out) {
    const f32x4* o4 = (const f32x4*)outs;
    const f32x4* l4 = (const f32x4*)labels;
    const i32x4* n4 = (const i32x4*)lens;

    // Block-contiguous 128KB span per array; thread strides BLOCK (4KB steps).
    const int base = blockIdx.x * (BLOCK * ITERS) + threadIdx.x;

    // Pipeline prologue: iterations 0..7 in flight (24 loads, 384B/thread).
    f32x4 o_s[DEPTH]; f32x4 l_s[DEPTH]; i32x4 n_s[DEPTH];
    #pragma unroll
    for (int j = 0; j < DEPTH; ++j) {
        o_s[j] = __builtin_nontemporal_load(o4 + base + j * BLOCK);
        l_s[j] = __builtin_nontemporal_load(l4 + base + j * BLOCK);
        n_s[j] = __builtin_nontemporal_load(n4 + base + j * BLOCK);
    }

    float acc = 0.0f;
    #pragma unroll
    for (int it = 0; it < ITERS - DEPTH; ++it) {
        // Issue iteration it+DEPTH before consuming iteration it.
        const int idx = base + (it + DEPTH) * BLOCK;
        f32x4 oN = __builtin_nontemporal_load(o4 + idx);
        f32x4 lN = __builtin_nontemporal_load(l4 + idx);
        i32x4 nN = __builtin_nontemporal_load(n4 + idx);

        acc += consume4(o_s[0], l_s[0], n_s[0]);

        // Rotate stages (fully unrolled => static indices, stays in VGPRs).
        #pragma unroll
        for (int j = 0; j < DEPTH - 1; ++j) {
            o_s[j] = o_s[j + 1]; l_s[j] = l_s[j + 1]; n_s[j] = n_s[j + 1];
        }
        o_s[DEPTH - 1] = oN; l_s[DEPTH - 1] = lN; n_s[DEPTH - 1] = nN;
    }
    #pragma unroll
    for (int j = 0; j < DEPTH; ++j)
        acc += consume4(o_s[j], l_s[j], n_s[j]);

    // wave-64 shuffle reduction
    #pragma unroll
    for (int off = 32; off > 0; off >>= 1)
        acc += __shfl_down(acc, off, 64);

    __shared__ float smem[BLOCK / 64];
    const int lane = threadIdx.x & 63;
    const int wid  = threadIdx.x >> 6;
    if (lane == 0) smem[wid] = acc;
    __syncthreads();
    if (threadIdx.x == 0) {
        float bsum = smem[0] + smem[1] + smem[2] + smem[3];
        atomicAdd(out, bsum);   // device-scope by default on CDNA
    }
}

extern "C" void kernel_launch(void* const* d_in, const int* in_sizes, int n_in,
                              void* d_out, int out_size, void* d_ws, size_t ws_size,
                              hipStream_t stream) {
    const float* outs   = (const float*)d_in[0];
    const float* labels = (const float*)d_in[1];
    const int*   lens   = (const int*)d_in[2];
    float* out = (float*)d_out;

    // d_out is poisoned 0xAA before every timed launch — zero it on-stream.
    hipMemsetAsync(out, 0, sizeof(float), stream);

    RegressionLoss_45440753992375_kernel<<<GRID, BLOCK, 0, stream>>>(outs, labels, lens, out);
}

// Round 13
// 176.639 us; speedup vs baseline: 1.0335x; 1.0041x over previous
//
#include <hip/hip_runtime.h>

// SmoothL1 (beta=0.5) masked sum reduction, N = 16M fixed.
// sl1 = ad < 0.5 ? d*d : ad - 0.25  (0.5*d*d/0.5 == d*d exactly: pow-2)
// mask: ad >= 1.0f/len; out[0] = sum(mask ? sl1 : 0)
//
// Ladder (warm us): plain=73 | sc1=74-75 | nt d1=51 | d2=45.6 | d3=44.6 |
// R13 3072x64KB d6 ~40 | R14 1536x128KB d6 ~37.9 (5.3 TB/s, OPTIMUM) |
// R15 768x256KB 41.7 (under-coverage) | R16 depth8 ~neutral (38-39).
// Depth + cursor axes spent. Fill-kernel reference: 6.6 TB/s (write).
//
// R17 (RESUBMIT — previous round was an infra failure, "container failed
// twice"; no measurement happened): WAVE-SEQUENTIAL WALK — last untested
// geometry cell. Every prior config interleaved the 4 waves at 1KB
// granularity / 4KB stride, so no wave-stream was ever sequential. Here
// wave w owns the contiguous 32KB quarter of its block's 128KB span,
// stepping 1KB per iteration:
//   addr = b*128KB + w*32KB + it*1KB + lane*16B
// -> 2048 wave-streams x 3 arrays, each perfectly sequential (the fill
// kernel's pattern, read-side). Single-variable vs R14 (geometry only;
// depth 6, nt, GRID=512, ITERS=32 unchanged). FP regrouping OK (R11).
// Predict: sequentiality real -> 34-36us warm (bench ~172-174);
// neutral/regress -> declare roofline at best config next round.

#define N_TOTAL 16777216
#define NVEC    (N_TOTAL / 4)       // 4194304 vec4 groups
#define BLOCK   256
#define GRID    512                 // 2 blocks/CU, 8 waves/CU
#define ITERS   (NVEC / (BLOCK * GRID))   // 32 iterations/thread, exact cover
#define WSPAN   (64 * ITERS)        // vec4 groups per wave span (32KB/16B=2048)

typedef float f32x4 __attribute__((ext_vector_type(4)));
typedef int   i32x4 __attribute__((ext_vector_type(4)));

__device__ __forceinline__ float sl1_term(float o, float l, int len) {
    float d  = o - l;
    float ad = fabsf(d);
    float v  = (ad < 0.5f) ? (d * d) : (ad - 0.25f);
    float boundary = 1.0f / (float)len;   // IEEE divide; matches jnp 1/len
    return (ad >= boundary) ? v : 0.0f;
}

__device__ __forceinline__ float consume4(f32x4 o, f32x4 l, i32x4 n) {
    float s = 0.0f;
    s += sl1_term(o.x, l.x, n.x);
    s += sl1_term(o.y, l.y, n.y);
    s += sl1_term(o.z, l.z, n.z);
    s += sl1_term(o.w, l.w, n.w);
    return s;
}

__global__ __launch_bounds__(BLOCK, 2) void RegressionLoss_45440753992375_kernel(
        const float* __restrict__ outs,
        const float* __restrict__ labels,
        const int*   __restrict__ lens,
        float* __restrict__ out) {
    const f32x4* o4 = (const f32x4*)outs;
    const f32x4* l4 = (const f32x4*)labels;
    const i32x4* n4 = (const i32x4*)lens;

    // Wave-sequential: wave w owns a contiguous 32KB quarter of the block's
    // 128KB span; successive iterations step 1KB (64 vec4 groups).
    const int lane = threadIdx.x & 63;
    const int wid  = threadIdx.x >> 6;
    const int base = blockIdx.x * (BLOCK * ITERS) + wid * WSPAN + lane;

    // Pipeline prologue: iterations 0..5 in flight (18 loads, 288B/thread).
    f32x4 oA = __builtin_nontemporal_load(o4 + base);
    f32x4 lA = __builtin_nontemporal_load(l4 + base);
    i32x4 nA = __builtin_nontemporal_load(n4 + base);

    f32x4 oB = __builtin_nontemporal_load(o4 + base + 1 * 64);
    f32x4 lB = __builtin_nontemporal_load(l4 + base + 1 * 64);
    i32x4 nB = __builtin_nontemporal_load(n4 + base + 1 * 64);

    f32x4 oC = __builtin_nontemporal_load(o4 + base + 2 * 64);
    f32x4 lC = __builtin_nontemporal_load(l4 + base + 2 * 64);
    i32x4 nC = __builtin_nontemporal_load(n4 + base + 2 * 64);

    f32x4 oD = __builtin_nontemporal_load(o4 + base + 3 * 64);
    f32x4 lD = __builtin_nontemporal_load(l4 + base + 3 * 64);
    i32x4 nD = __builtin_nontemporal_load(n4 + base + 3 * 64);

    f32x4 oE = __builtin_nontemporal_load(o4 + base + 4 * 64);
    f32x4 lE = __builtin_nontemporal_load(l4 + base + 4 * 64);
    i32x4 nE = __builtin_nontemporal_load(n4 + base + 4 * 64);

    f32x4 oF = __builtin_nontemporal_load(o4 + base + 5 * 64);
    f32x4 lF = __builtin_nontemporal_load(l4 + base + 5 * 64);
    i32x4 nF = __builtin_nontemporal_load(n4 + base + 5 * 64);

    float acc = 0.0f;
    #pragma unroll
    for (int it = 0; it < ITERS - 6; ++it) {
        // Issue iteration it+6 (21 outstanding peak) before consuming it.
        const int idx = base + (it + 6) * 64;
        f32x4 oG = __builtin_nontemporal_load(o4 + idx);
        f32x4 lG = __builtin_nontemporal_load(l4 + idx);
        i32x4 nG = __builtin_nontemporal_load(n4 + idx);

        acc += consume4(oA, lA, nA);

        // Rotate stages (register renaming; loop fully unrolled).
        oA = oB; lA = lB; nA = nB;
        oB = oC; lB = lC; nB = nC;
        oC = oD; lC = lD; nC = nD;
        oD = oE; lD = lE; nD = nE;
        oE = oF; lE = lF; nE = nF;
        oF = oG; lF = lG; nF = nG;
    }
    acc += consume4(oA, lA, nA);   // iteration ITERS-6
    acc += consume4(oB, lB, nB);   // iteration ITERS-5
    acc += consume4(oC, lC, nC);   // iteration ITERS-4
    acc += consume4(oD, lD, nD);   // iteration ITERS-3
    acc += consume4(oE, lE, nE);   // iteration ITERS-2
    acc += consume4(oF, lF, nF);   // iteration ITERS-1

    // wave-64 shuffle reduction
    #pragma unroll
    for (int off = 32; off > 0; off >>= 1)
        acc += __shfl_down(acc, off, 64);

    __shared__ float smem[BLOCK / 64];
    if (lane == 0) smem[wid] = acc;
    __syncthreads();
    if (threadIdx.x == 0) {
        float bsum = smem[0] + smem[1] + smem[2] + smem[3];
        atomicAdd(out, bsum);   // device-scope by default on CDNA
    }
}

extern "C" void kernel_launch(void* const* d_in, const int* in_sizes, int n_in,
                              void* d_out, int out_size, void* d_ws, size_t ws_size,
                              hipStream_t stream) {
    const float* outs   = (const float*)d_in[0];
    const float* labels = (const float*)d_in[1];
    const int*   lens   = (const int*)d_in[2];
    float* out = (float*)d_out;

    // d_out is poisoned 0xAA before every timed launch — zero it on-stream.
    hipMemsetAsync(out, 0, sizeof(float), stream);

    RegressionLoss_45440753992375_kernel<<<GRID, BLOCK, 0, stream>>>(outs, labels, lens, out);
}